// Round 1
// baseline (507.730 us; speedup 1.0000x reference)
//
#include <hip/hip_runtime.h>

#define D 64
#define K 512

// Kernel A: transpose embeddings (D,K) -> embT (K,D) and compute ||e_k||^2.
// Reads are coalesced across k (consecutive lanes -> consecutive addresses).
__global__ void vq_prep(const float* __restrict__ emb,
                        float* __restrict__ embT,
                        float* __restrict__ enorm) {
    int k = blockIdx.x * blockDim.x + threadIdx.x;
    if (k >= K) return;
    float s = 0.f;
#pragma unroll
    for (int d = 0; d < D; ++d) {
        float v = emb[d * K + k];
        embT[k * D + d] = v;
        s += v * v;
    }
    enorm[k] = s;
}

// Kernel B: one thread per row. Row x lives in 16 float4 VGPRs; the codebook
// is scanned with wave-uniform indices so the compiler can use scalar loads.
// dist = (||x||^2 + ||e||^2) - 2*dot, strict < keeps the FIRST minimum
// (matches np.argmin tie-break).
__global__ __launch_bounds__(256) void vq_main(const float* __restrict__ x,
                                               const float* __restrict__ embT,
                                               const float* __restrict__ enorm,
                                               float* __restrict__ outq,
                                               float* __restrict__ outidx,
                                               int nrows) {
    int r = blockIdx.x * blockDim.x + threadIdx.x;
    if (r >= nrows) return;

    const float4* xf4 = (const float4*)(x + (size_t)r * D);
    float4 xv[16];
#pragma unroll
    for (int j = 0; j < 16; ++j) xv[j] = xf4[j];

    float xn = 0.f;
#pragma unroll
    for (int j = 0; j < 16; ++j)
        xn += xv[j].x * xv[j].x + xv[j].y * xv[j].y +
              xv[j].z * xv[j].z + xv[j].w * xv[j].w;

    float best = 3.4e38f;
    int bidx = 0;
    const float4* ef4 = (const float4*)embT;
    for (int k = 0; k < K; ++k) {
        float dot = 0.f;
#pragma unroll
        for (int j = 0; j < 16; ++j) {
            float4 e = ef4[k * 16 + j];   // wave-uniform -> scalar load
            dot += xv[j].x * e.x + xv[j].y * e.y +
                   xv[j].z * e.z + xv[j].w * e.w;
        }
        float dist = (xn + enorm[k]) - 2.0f * dot;
        if (dist < best) { best = dist; bidx = k; }
    }

    // gather winning codeword (per-lane scattered, L2-resident: only 128 KB)
    float4* oq = (float4*)(outq + (size_t)r * D);
    const float4* eb = (const float4*)(embT + (size_t)bidx * D);
#pragma unroll
    for (int j = 0; j < 16; ++j) oq[j] = eb[j];

    outidx[r] = (float)bidx;
}

extern "C" void kernel_launch(void* const* d_in, const int* in_sizes, int n_in,
                              void* d_out, int out_size, void* d_ws, size_t ws_size,
                              hipStream_t stream) {
    const float* x   = (const float*)d_in[0];   // (64,32,32,64) f32
    const float* emb = (const float*)d_in[1];   // (64,512) f32

    int nrows = in_sizes[0] / D;                // 65536

    float* embT  = (float*)d_ws;                       // K*D floats = 128 KiB
    float* enorm = (float*)d_ws + (size_t)K * D;       // K floats

    float* outq   = (float*)d_out;                     // nrows*D floats
    float* outidx = (float*)d_out + (size_t)nrows * D; // nrows floats (indices as f32)

    vq_prep<<<(K + 255) / 256, 256, 0, stream>>>(emb, embT, enorm);
    vq_main<<<(nrows + 255) / 256, 256, 0, stream>>>(x, embT, enorm,
                                                     outq, outidx, nrows);
}

// Round 2
// 256.511 us; speedup vs baseline: 1.9794x; 1.9794x over previous
//
#include <hip/hip_runtime.h>

#define D 64
#define K 512
#define ROWS_PB 64
#define SEGS 4
#define SEG_K (K / SEGS)   // 128

// Kernel A: transpose embeddings (D,K) -> embT (K,D) and compute ||e_k||^2.
__global__ void vq_prep(const float* __restrict__ emb,
                        float* __restrict__ embT,
                        float* __restrict__ enorm) {
    int k = blockIdx.x * blockDim.x + threadIdx.x;
    if (k >= K) return;
    float s = 0.f;
#pragma unroll
    for (int d = 0; d < D; ++d) {
        float v = emb[d * K + k];
        embT[k * D + d] = v;
        s += v * v;
    }
    enorm[k] = s;
}

// Block = 64 rows x 4 waves. Wave w scans codebook segment [w*128, w*128+128);
// lane = row within block. k is wave-uniform -> codebook reads stay scalar
// loads. Row x held in 16 float4 VGPRs (launch_bounds gives 128-VGPR budget).
// 4 independent FMA accumulator chains for ILP. Cross-segment combine in LDS
// with ascending-segment strict < (first-occurrence tie-break, matches
// np.argmin). Cooperative coalesced gather for the quantized output.
__global__ __launch_bounds__(256, 4) void vq_main(
    const float* __restrict__ x,
    const float* __restrict__ embT,
    const float* __restrict__ enorm,
    float* __restrict__ outq,
    float* __restrict__ outidx,
    int nrows) {
    const int tid  = threadIdx.x;
    const int wave = tid >> 6;          // segment 0..3
    const int lane = tid & 63;          // row within block
    const int row0 = blockIdx.x * ROWS_PB;
    const int r    = row0 + lane;
    if (r >= nrows) return;             // nrows is a multiple of 64; never taken

    __shared__ float smin[SEGS][ROWS_PB];
    __shared__ int   sidx[SEGS][ROWS_PB];
    __shared__ int   sfin[ROWS_PB];

    // row into registers (64 floats = 16 float4)
    const float4* xf4 = (const float4*)(x + (size_t)r * D);
    float4 xv[16];
#pragma unroll
    for (int j = 0; j < 16; ++j) xv[j] = xf4[j];

    float xn = 0.f;
#pragma unroll
    for (int j = 0; j < 16; ++j)
        xn += xv[j].x * xv[j].x + xv[j].y * xv[j].y +
              xv[j].z * xv[j].z + xv[j].w * xv[j].w;

    const int k0 = wave * SEG_K;
    float best = 3.4e38f;
    int   bidx = k0;

    const float4* ef4 = (const float4*)embT;
#pragma unroll 2
    for (int k = k0; k < k0 + SEG_K; ++k) {
        float d0 = 0.f, d1 = 0.f, d2 = 0.f, d3 = 0.f;  // 4 independent chains
#pragma unroll
        for (int j = 0; j < 4; ++j) {
            float4 e0 = ef4[k * 16 + j * 4 + 0];   // wave-uniform -> s_load
            float4 e1 = ef4[k * 16 + j * 4 + 1];
            float4 e2 = ef4[k * 16 + j * 4 + 2];
            float4 e3 = ef4[k * 16 + j * 4 + 3];
            d0 += xv[j*4+0].x*e0.x + xv[j*4+0].y*e0.y + xv[j*4+0].z*e0.z + xv[j*4+0].w*e0.w;
            d1 += xv[j*4+1].x*e1.x + xv[j*4+1].y*e1.y + xv[j*4+1].z*e1.z + xv[j*4+1].w*e1.w;
            d2 += xv[j*4+2].x*e2.x + xv[j*4+2].y*e2.y + xv[j*4+2].z*e2.z + xv[j*4+2].w*e2.w;
            d3 += xv[j*4+3].x*e3.x + xv[j*4+3].y*e3.y + xv[j*4+3].z*e3.z + xv[j*4+3].w*e3.w;
        }
        float dist = (xn + enorm[k]) - 2.0f * ((d0 + d1) + (d2 + d3));
        if (dist < best) { best = dist; bidx = k; }
    }

    smin[wave][lane] = best;
    sidx[wave][lane] = bidx;
    __syncthreads();

    if (wave == 0) {
        float b  = smin[0][lane];
        int   bi = sidx[0][lane];
#pragma unroll
        for (int s = 1; s < SEGS; ++s) {   // ascending segment, strict <
            float dv = smin[s][lane];
            int   di = sidx[s][lane];
            if (dv < b) { b = dv; bi = di; }
        }
        sfin[lane] = bi;
        outidx[r]  = (float)bi;
    }
    __syncthreads();

    // cooperative coalesced gather+write: 64 rows x 16 float4 = 1024 float4
    float4* oq4 = (float4*)(outq + (size_t)row0 * D);
#pragma unroll
    for (int i = 0; i < 4; ++i) {
        int f  = tid + i * 256;       // 0..1023
        int rr = f >> 4;
        int j  = f & 15;
        oq4[f] = ef4[sfin[rr] * 16 + j];
    }
}

extern "C" void kernel_launch(void* const* d_in, const int* in_sizes, int n_in,
                              void* d_out, int out_size, void* d_ws, size_t ws_size,
                              hipStream_t stream) {
    const float* x   = (const float*)d_in[0];   // (64,32,32,64) f32
    const float* emb = (const float*)d_in[1];   // (64,512) f32

    int nrows = in_sizes[0] / D;                // 65536

    float* embT  = (float*)d_ws;                       // K*D floats = 128 KiB
    float* enorm = (float*)d_ws + (size_t)K * D;       // K floats

    float* outq   = (float*)d_out;                     // nrows*D floats
    float* outidx = (float*)d_out + (size_t)nrows * D; // nrows floats

    vq_prep<<<(K + 255) / 256, 256, 0, stream>>>(emb, embT, enorm);
    vq_main<<<(nrows + ROWS_PB - 1) / ROWS_PB, 256, 0, stream>>>(
        x, embT, enorm, outq, outidx, nrows);
}

// Round 3
// 103.003 us; speedup vs baseline: 4.9293x; 2.4903x over previous
//
#include <hip/hip_runtime.h>

#define D 64
#define K 512
#define ROWS_PB 64
#define SEGS 8
#define SEG_K (K / SEGS)   // 64

// Kernel A: transpose embeddings (D,K) -> embT (K,D) and compute ||e_k||^2.
__global__ void vq_prep(const float* __restrict__ emb,
                        float* __restrict__ embT,
                        float* __restrict__ enorm) {
    int k = blockIdx.x * blockDim.x + threadIdx.x;
    if (k >= K) return;
    float s = 0.f;
#pragma unroll
    for (int d = 0; d < D; ++d) {
        float v = emb[d * K + k];
        embT[k * D + d] = v;
        s += v * v;
    }
    enorm[k] = s;
}

// Block = 64 rows x 8 waves (512 threads). Wave w scans codebook segment
// [w*64, w*64+64); lane = row within block. Row x is PINNED in 64 VGPRs via
// inline-asm keep-alive (round-2 post-mortem: compiler sank x loads into the
// k-loop, VGPR_Count=64 proved x was re-read from L1 every iteration).
// readfirstlane makes the segment id provably wave-uniform so codebook reads
// go down the scalar-load path (zero VALU cost). Ascending-segment strict <
// combine preserves np.argmin first-occurrence tie-break.
__global__ __launch_bounds__(512, 4) void vq_main(
    const float* __restrict__ x,
    const float* __restrict__ embT,
    const float* __restrict__ enorm,
    float* __restrict__ outq,
    float* __restrict__ outidx,
    int nrows) {
    const int tid  = threadIdx.x;
    const int wave = __builtin_amdgcn_readfirstlane(tid >> 6);  // 0..7
    const int lane = tid & 63;                                  // row in block
    const int row0 = blockIdx.x * ROWS_PB;
    const int r    = row0 + lane;   // grid is sized exactly: r < nrows always

    __shared__ float smin[SEGS][ROWS_PB];
    __shared__ int   sidx[SEGS][ROWS_PB];
    __shared__ int   sfin[ROWS_PB];

    // row into registers (64 floats = 16 float4), then pin them in VGPRs
    const float4* xf4 = (const float4*)(x + (size_t)r * D);
    float4 xv[16];
#pragma unroll
    for (int j = 0; j < 16; ++j) xv[j] = xf4[j];
#pragma unroll
    for (int j = 0; j < 16; ++j)
        asm volatile("" : "+v"(xv[j].x), "+v"(xv[j].y),
                          "+v"(xv[j].z), "+v"(xv[j].w));

    float xn = 0.f;
#pragma unroll
    for (int j = 0; j < 16; ++j)
        xn += xv[j].x * xv[j].x + xv[j].y * xv[j].y +
              xv[j].z * xv[j].z + xv[j].w * xv[j].w;

    const int k0 = wave * SEG_K;
    float best = 3.4e38f;
    int   bidx = k0;

    const float4* ef4 = (const float4*)embT;
#pragma unroll 2
    for (int k = k0; k < k0 + SEG_K; ++k) {
        float d0 = 0.f, d1 = 0.f, d2 = 0.f, d3 = 0.f;  // 4 independent chains
#pragma unroll
        for (int j = 0; j < 4; ++j) {
            float4 e0 = ef4[k * 16 + j * 4 + 0];   // wave-uniform -> scalar
            float4 e1 = ef4[k * 16 + j * 4 + 1];
            float4 e2 = ef4[k * 16 + j * 4 + 2];
            float4 e3 = ef4[k * 16 + j * 4 + 3];
            d0 += xv[j*4+0].x*e0.x + xv[j*4+0].y*e0.y + xv[j*4+0].z*e0.z + xv[j*4+0].w*e0.w;
            d1 += xv[j*4+1].x*e1.x + xv[j*4+1].y*e1.y + xv[j*4+1].z*e1.z + xv[j*4+1].w*e1.w;
            d2 += xv[j*4+2].x*e2.x + xv[j*4+2].y*e2.y + xv[j*4+2].z*e2.z + xv[j*4+2].w*e2.w;
            d3 += xv[j*4+3].x*e3.x + xv[j*4+3].y*e3.y + xv[j*4+3].z*e3.z + xv[j*4+3].w*e3.w;
        }
        float dist = (xn + enorm[k]) - 2.0f * ((d0 + d1) + (d2 + d3));
        if (dist < best) { best = dist; bidx = k; }
    }

    smin[wave][lane] = best;
    sidx[wave][lane] = bidx;
    __syncthreads();

    if (wave == 0) {
        float b  = smin[0][lane];
        int   bi = sidx[0][lane];
#pragma unroll
        for (int s = 1; s < SEGS; ++s) {   // ascending segment, strict <
            float dv = smin[s][lane];
            int   di = sidx[s][lane];
            if (dv < b) { b = dv; bi = di; }
        }
        sfin[lane] = bi;
        outidx[r]  = (float)bi;
    }
    __syncthreads();

    // cooperative coalesced gather+write: 64 rows x 16 float4 = 1024 float4
    float4* oq4 = (float4*)(outq + (size_t)row0 * D);
#pragma unroll
    for (int i = 0; i < 2; ++i) {
        int f  = tid + i * 512;       // 0..1023
        int rr = f >> 4;
        int j  = f & 15;
        oq4[f] = ef4[sfin[rr] * 16 + j];
    }
}

extern "C" void kernel_launch(void* const* d_in, const int* in_sizes, int n_in,
                              void* d_out, int out_size, void* d_ws, size_t ws_size,
                              hipStream_t stream) {
    const float* x   = (const float*)d_in[0];   // (64,32,32,64) f32
    const float* emb = (const float*)d_in[1];   // (64,512) f32

    int nrows = in_sizes[0] / D;                // 65536

    float* embT  = (float*)d_ws;                       // K*D floats = 128 KiB
    float* enorm = (float*)d_ws + (size_t)K * D;       // K floats

    float* outq   = (float*)d_out;                     // nrows*D floats
    float* outidx = (float*)d_out + (size_t)nrows * D; // nrows floats

    vq_prep<<<(K + 255) / 256, 256, 0, stream>>>(emb, embT, enorm);
    vq_main<<<nrows / ROWS_PB, 512, 0, stream>>>(
        x, embT, enorm, outq, outidx, nrows);
}

// Round 4
// 65.855 us; speedup vs baseline: 7.7098x; 1.5641x over previous
//
#include <hip/hip_runtime.h>

#define D 64
#define K 512
#define NT (K / 16)          // 32 codeword tiles
#define TAU 0.01f            // proxy-margin threshold (dist-gap 0.02)
#define FLAG_CAP 16384

typedef float  f32x4  __attribute__((ext_vector_type(4)));
typedef short  bf16x8 __attribute__((ext_vector_type(8)));

__device__ inline unsigned short bf16_rne(float f) {
    union { float f; unsigned u; } v; v.f = f;
    unsigned r = v.u + 0x7FFFu + ((v.u >> 16) & 1u);
    return (unsigned short)(r >> 16);
}
__device__ inline float bf16_val(unsigned short b) {
    union { float f; unsigned u; } v; v.u = ((unsigned)b) << 16;
    return v.f;
}
// split 8 consecutive floats into bf16 hi + lo fragments
__device__ inline void split8(const float* p, bf16x8& h, bf16x8& l) {
    float4 a = *(const float4*)p;
    float4 b = *(const float4*)(p + 4);
    float f[8] = {a.x, a.y, a.z, a.w, b.x, b.y, b.z, b.w};
#pragma unroll
    for (int j = 0; j < 8; ++j) {
        unsigned short hb = bf16_rne(f[j]);
        float lo = f[j] - bf16_val(hb);
        h[j] = (short)hb;
        l[j] = (short)bf16_rne(lo);
    }
}

// Prep (4096 threads): build fragment-linear bf16 hi/lo B-operand from emb
// (emb is (D,K) = B[k_gemm=d][n=codeword] directly), plus embT + ||e||^2.
// B-frag layout (16x16x32): col n = lane&15, k-elems d = c*32+(lane>>4)*8+j.
__global__ void vq_prep(const float* __restrict__ emb,
                        float* __restrict__ embT,
                        float* __restrict__ enorm,
                        bf16x8* __restrict__ bhi,
                        bf16x8* __restrict__ blo) {
    int t = blockIdx.x * blockDim.x + threadIdx.x;   // 0..4095
    int nt = t >> 7, c = (t >> 6) & 1, lane = t & 63;
    int k  = nt * 16 + (lane & 15);
    int d0 = c * 32 + ((lane >> 4) << 3);
    bf16x8 h, l;
#pragma unroll
    for (int j = 0; j < 8; ++j) {
        float xv = emb[(d0 + j) * K + k];
        unsigned short hb = bf16_rne(xv);
        float lo = xv - bf16_val(hb);
        h[j] = (short)hb;
        l[j] = (short)bf16_rne(lo);
    }
    int off = (nt * 2 + c) * 64 + lane;
    bhi[off] = h; blo[off] = l;

    if (t < K) {    // job 2: transpose + norms
        float s = 0.f;
#pragma unroll
        for (int d = 0; d < D; ++d) {
            float v = emb[d * K + t];
            embT[t * D + d] = v;
            s += v * v;
        }
        enorm[t] = s;
    }
}

// Phase 1: wave = 2 row-tiles (32 rows) x all 512 codewords.
// acc init = -0.5*||e||^2  =>  argmax(acc) == argmin(dist); xn drops out.
// 3-product bf16-split MFMA (hi*hi + hi*lo + lo*hi). Track top-2 per row;
// margin < TAU rows go to a flag list for exact fp32 re-solve (phase 2).
__global__ __launch_bounds__(256, 2) void vq_mfma(
    const float* __restrict__ x,
    const float* __restrict__ embT,
    const float* __restrict__ enorm,
    const bf16x8* __restrict__ bhi,
    const bf16x8* __restrict__ blo,
    float* __restrict__ outq,
    float* __restrict__ outidx,
    int* __restrict__ flagcnt,
    int* __restrict__ flagrows) {
    const int tid  = threadIdx.x;
    const int wave = __builtin_amdgcn_readfirstlane(tid >> 6);
    const int lane = tid & 63;
    const int col  = lane & 15;   // A-row-in-tile for A-frag; codeword for B/C
    const int grp  = lane >> 4;
    const int rt0  = (blockIdx.x * 4 + wave) * 2;

    // A fragments (16x16x32): row m = lane&15, k = (lane>>4)*8 + j (+32*c)
    bf16x8 ah[2][2], al[2][2];
#pragma unroll
    for (int t = 0; t < 2; ++t) {
        const float* xr = x + (size_t)((rt0 + t) * 16 + col) * D + grp * 8;
        split8(xr,      ah[t][0], al[t][0]);
        split8(xr + 32, ah[t][1], al[t][1]);
    }

    float b1[2][4], b2[2][4];
    int   bi[2][4];
#pragma unroll
    for (int t = 0; t < 2; ++t)
#pragma unroll
        for (int q = 0; q < 4; ++q) {
            b1[t][q] = -3.4e38f; b2[t][q] = -3.4e38f; bi[t][q] = 0;
        }

#pragma unroll 2
    for (int nt = 0; nt < NT; ++nt) {
        int fo = (nt * 2) * 64 + lane;
        bf16x8 bh0 = bhi[fo], bh1 = bhi[fo + 64];
        bf16x8 bl0 = blo[fo], bl1 = blo[fo + 64];
        float env = enorm[nt * 16 + col] * -0.5f;
        f32x4 acc[2];
#pragma unroll
        for (int t = 0; t < 2; ++t) {
            acc[t] = f32x4{env, env, env, env};
            acc[t] = __builtin_amdgcn_mfma_f32_16x16x32_bf16(ah[t][0], bh0, acc[t], 0, 0, 0);
            acc[t] = __builtin_amdgcn_mfma_f32_16x16x32_bf16(ah[t][1], bh1, acc[t], 0, 0, 0);
            acc[t] = __builtin_amdgcn_mfma_f32_16x16x32_bf16(ah[t][0], bl0, acc[t], 0, 0, 0);
            acc[t] = __builtin_amdgcn_mfma_f32_16x16x32_bf16(ah[t][1], bl1, acc[t], 0, 0, 0);
            acc[t] = __builtin_amdgcn_mfma_f32_16x16x32_bf16(al[t][0], bh0, acc[t], 0, 0, 0);
            acc[t] = __builtin_amdgcn_mfma_f32_16x16x32_bf16(al[t][1], bh1, acc[t], 0, 0, 0);
        }
        int kk = nt * 16 + col;
#pragma unroll
        for (int t = 0; t < 2; ++t)
#pragma unroll
            for (int q = 0; q < 4; ++q) {
                float v = acc[t][q];
                bool gt = v > b1[t][q];     // strict: first occurrence wins
                b2[t][q] = gt ? b1[t][q] : fmaxf(b2[t][q], v);
                b1[t][q] = gt ? v : b1[t][q];
                bi[t][q] = gt ? kk : bi[t][q];
            }
    }

    // reduce across the 16 codeword-columns within each 16-lane group
#pragma unroll
    for (int t = 0; t < 2; ++t)
#pragma unroll
        for (int q = 0; q < 4; ++q) {
            float v1 = b1[t][q], v2 = b2[t][q];
            int   i1 = bi[t][q];
#pragma unroll
            for (int m = 1; m <= 8; m <<= 1) {
                float o1 = __shfl_xor(v1, m);
                float o2 = __shfl_xor(v2, m);
                int   oi = __shfl_xor(i1, m);
                float nb2 = fmaxf(fminf(v1, o1), fmaxf(v2, o2));
                if (o1 > v1 || (o1 == v1 && oi < i1)) { v1 = o1; i1 = oi; }
                v2 = nb2;
            }
            b1[t][q] = v1; b2[t][q] = v2; bi[t][q] = i1;
        }

    // writes: C-layout row = (lane>>4)*4 + q, col = lane&15
#pragma unroll
    for (int t = 0; t < 2; ++t) {
        int rbase = (rt0 + t) * 16;
#pragma unroll
        for (int q = 0; q < 4; ++q) {
            if (col == q) {
                int row = rbase + grp * 4 + q;
                outidx[row] = (float)bi[t][q];
                if (b1[t][q] - b2[t][q] < TAU) {
                    int pos = atomicAdd(flagcnt, 1);
                    if (pos < FLAG_CAP) flagrows[pos] = row;
                }
            }
        }
#pragma unroll
        for (int g = 0; g < 4; ++g)
#pragma unroll
            for (int q = 0; q < 4; ++q) {
                int kidx = __shfl(bi[t][q], g * 16);
                int row  = rbase + g * 4 + q;
                outq[(size_t)row * D + lane] = embT[(size_t)kidx * D + lane];
            }
    }
}

// Phase 2: exact fp32 re-solve of flagged rows (wave per row; lane owns 8 k).
// Same distance formula/chain structure as the proven round-3 kernel.
__global__ __launch_bounds__(256) void vq_fix(
    const float* __restrict__ x,
    const float* __restrict__ embT,
    const float* __restrict__ enorm,
    const int* __restrict__ flagcnt,
    const int* __restrict__ flagrows,
    float* __restrict__ outq,
    float* __restrict__ outidx) {
    int lane = threadIdx.x & 63;
    int wid  = (blockIdx.x * blockDim.x + threadIdx.x) >> 6;
    int nw   = (gridDim.x * blockDim.x) >> 6;
    int cnt  = *flagcnt; if (cnt > FLAG_CAP) cnt = FLAG_CAP;

    for (int i = wid; i < cnt; i += nw) {
        int row = __builtin_amdgcn_readfirstlane(flagrows[i]);
        const float4* x4 = (const float4*)(x + (size_t)row * D);

        float xn = 0.f;
#pragma unroll
        for (int j = 0; j < 16; ++j) {
            float4 xv = x4[j];
            xn += xv.x * xv.x + xv.y * xv.y + xv.z * xv.z + xv.w * xv.w;
        }

        float best = 3.4e38f; int bidx = 0;
#pragma unroll
        for (int kk = 0; kk < 8; ++kk) {
            int k = lane * 8 + kk;
            const float4* e4 = (const float4*)(embT + (size_t)k * D);
            float d0 = 0.f, d1 = 0.f, d2 = 0.f, d3 = 0.f;
#pragma unroll
            for (int j = 0; j < 4; ++j) {
                float4 e0 = e4[j*4+0], e1 = e4[j*4+1], e2 = e4[j*4+2], e3 = e4[j*4+3];
                float4 x0 = x4[j*4+0], x1 = x4[j*4+1], x2 = x4[j*4+2], x3 = x4[j*4+3];
                d0 += x0.x*e0.x + x0.y*e0.y + x0.z*e0.z + x0.w*e0.w;
                d1 += x1.x*e1.x + x1.y*e1.y + x1.z*e1.z + x1.w*e1.w;
                d2 += x2.x*e2.x + x2.y*e2.y + x2.z*e2.z + x2.w*e2.w;
                d3 += x3.x*e3.x + x3.y*e3.y + x3.z*e3.z + x3.w*e3.w;
            }
            float dist = (xn + enorm[k]) - 2.0f * ((d0 + d1) + (d2 + d3));
            if (dist < best) { best = dist; bidx = k; }   // ascending k in lane
        }
#pragma unroll
        for (int m = 1; m <= 32; m <<= 1) {
            float od = __shfl_xor(best, m);
            int   oi = __shfl_xor(bidx, m);
            if (od < best || (od == best && oi < bidx)) { best = od; bidx = oi; }
        }
        if (lane == 0) outidx[row] = (float)bidx;
        outq[(size_t)row * D + lane] = embT[(size_t)bidx * D + lane];
    }
}

extern "C" void kernel_launch(void* const* d_in, const int* in_sizes, int n_in,
                              void* d_out, int out_size, void* d_ws, size_t ws_size,
                              hipStream_t stream) {
    const float* x   = (const float*)d_in[0];   // (64,32,32,64) f32
    const float* emb = (const float*)d_in[1];   // (64,512) f32
    int nrows = in_sizes[0] / D;                // 65536

    char* w = (char*)d_ws;
    float*  embT   = (float*)w;   w += (size_t)K * D * 4;     // 128 KiB
    float*  enorm  = (float*)w;   w += (size_t)K * 4;         // 2 KiB
    bf16x8* bhi    = (bf16x8*)w;  w += (size_t)NT * 2 * 64 * 16; // 64 KiB
    bf16x8* blo    = (bf16x8*)w;  w += (size_t)NT * 2 * 64 * 16; // 64 KiB
    int*    flagcnt  = (int*)w;   w += 256;
    int*    flagrows = (int*)w;                               // 64 KiB

    float* outq   = (float*)d_out;
    float* outidx = (float*)d_out + (size_t)nrows * D;

    hipMemsetAsync(flagcnt, 0, 4, stream);
    vq_prep<<<16, 256, 0, stream>>>(emb, embT, enorm, bhi, blo);
    vq_mfma<<<nrows / 128, 256, 0, stream>>>(x, embT, enorm, bhi, blo,
                                             outq, outidx, flagcnt, flagrows);
    vq_fix<<<128, 256, 0, stream>>>(x, embT, enorm, flagcnt, flagrows,
                                    outq, outidx);
}

// Round 5
// 61.081 us; speedup vs baseline: 8.3124x; 1.0782x over previous
//
#include <hip/hip_runtime.h>

#define D 64
#define K 512
#define NT (K / 16)          // 32 codeword tiles
#define TAU 0.01f            // proxy-margin threshold (dist-gap 0.02)
#define FLAG_CAP 16384

typedef float  f32x4  __attribute__((ext_vector_type(4)));
typedef short  bf16x8 __attribute__((ext_vector_type(8)));

__device__ inline unsigned short bf16_rne(float f) {
    union { float f; unsigned u; } v; v.f = f;
    unsigned r = v.u + 0x7FFFu + ((v.u >> 16) & 1u);
    return (unsigned short)(r >> 16);
}
__device__ inline float bf16_val(unsigned short b) {
    union { float f; unsigned u; } v; v.u = ((unsigned)b) << 16;
    return v.f;
}
// split 8 consecutive floats into bf16 hi + lo fragments
__device__ inline void split8(const float* p, bf16x8& h, bf16x8& l) {
    float4 a = *(const float4*)p;
    float4 b = *(const float4*)(p + 4);
    float f[8] = {a.x, a.y, a.z, a.w, b.x, b.y, b.z, b.w};
#pragma unroll
    for (int j = 0; j < 8; ++j) {
        unsigned short hb = bf16_rne(f[j]);
        float lo = f[j] - bf16_val(hb);
        h[j] = (short)hb;
        l[j] = (short)bf16_rne(lo);
    }
}

// Prep (4096 threads): build fragment-linear bf16 hi/lo B-operand from emb
// (emb is (D,K) = B[k_gemm=d][n=codeword] directly), plus embT + ||e||^2.
// Also zeroes flagcnt (round-4 post-mortem: a hipMemsetAsync node in the
// graph cost ~42 us/replay as fillBufferAligned — 2/3 of total time).
__global__ void vq_prep(const float* __restrict__ emb,
                        float* __restrict__ embT,
                        float* __restrict__ enorm,
                        bf16x8* __restrict__ bhi,
                        bf16x8* __restrict__ blo,
                        int* __restrict__ flagcnt) {
    int t = blockIdx.x * blockDim.x + threadIdx.x;   // 0..4095
    if (t == 0) *flagcnt = 0;   // visible to vq_mfma via stream order
    int nt = t >> 7, c = (t >> 6) & 1, lane = t & 63;
    int k  = nt * 16 + (lane & 15);
    int d0 = c * 32 + ((lane >> 4) << 3);
    bf16x8 h, l;
#pragma unroll
    for (int j = 0; j < 8; ++j) {
        float xv = emb[(d0 + j) * K + k];
        unsigned short hb = bf16_rne(xv);
        float lo = xv - bf16_val(hb);
        h[j] = (short)hb;
        l[j] = (short)bf16_rne(lo);
    }
    int off = (nt * 2 + c) * 64 + lane;
    bhi[off] = h; blo[off] = l;

    if (t < K) {    // job 2: transpose + norms
        float s = 0.f;
#pragma unroll
        for (int d = 0; d < D; ++d) {
            float v = emb[d * K + t];
            embT[t * D + d] = v;
            s += v * v;
        }
        enorm[t] = s;
    }
}

// Phase 1: wave = 2 row-tiles (32 rows) x all 512 codewords.
// acc init = -0.5*||e||^2  =>  argmax(acc) == argmin(dist); xn drops out.
// 3-product bf16-split MFMA (hi*hi + hi*lo + lo*hi). Track top-2 per row;
// margin < TAU rows go to a flag list for exact fp32 re-solve (phase 2).
__global__ __launch_bounds__(256, 2) void vq_mfma(
    const float* __restrict__ x,
    const float* __restrict__ embT,
    const float* __restrict__ enorm,
    const bf16x8* __restrict__ bhi,
    const bf16x8* __restrict__ blo,
    float* __restrict__ outq,
    float* __restrict__ outidx,
    int* __restrict__ flagcnt,
    int* __restrict__ flagrows) {
    const int tid  = threadIdx.x;
    const int wave = __builtin_amdgcn_readfirstlane(tid >> 6);
    const int lane = tid & 63;
    const int col  = lane & 15;   // A-row-in-tile for A-frag; codeword for B/C
    const int grp  = lane >> 4;
    const int rt0  = (blockIdx.x * 4 + wave) * 2;

    // A fragments (16x16x32): row m = lane&15, k = (lane>>4)*8 + j (+32*c)
    bf16x8 ah[2][2], al[2][2];
#pragma unroll
    for (int t = 0; t < 2; ++t) {
        const float* xr = x + (size_t)((rt0 + t) * 16 + col) * D + grp * 8;
        split8(xr,      ah[t][0], al[t][0]);
        split8(xr + 32, ah[t][1], al[t][1]);
    }

    float b1[2][4], b2[2][4];
    int   bi[2][4];
#pragma unroll
    for (int t = 0; t < 2; ++t)
#pragma unroll
        for (int q = 0; q < 4; ++q) {
            b1[t][q] = -3.4e38f; b2[t][q] = -3.4e38f; bi[t][q] = 0;
        }

#pragma unroll 2
    for (int nt = 0; nt < NT; ++nt) {
        int fo = (nt * 2) * 64 + lane;
        bf16x8 bh0 = bhi[fo], bh1 = bhi[fo + 64];
        bf16x8 bl0 = blo[fo], bl1 = blo[fo + 64];
        float env = enorm[nt * 16 + col] * -0.5f;
        f32x4 acc[2];
#pragma unroll
        for (int t = 0; t < 2; ++t) {
            acc[t] = f32x4{env, env, env, env};
            acc[t] = __builtin_amdgcn_mfma_f32_16x16x32_bf16(ah[t][0], bh0, acc[t], 0, 0, 0);
            acc[t] = __builtin_amdgcn_mfma_f32_16x16x32_bf16(ah[t][1], bh1, acc[t], 0, 0, 0);
            acc[t] = __builtin_amdgcn_mfma_f32_16x16x32_bf16(ah[t][0], bl0, acc[t], 0, 0, 0);
            acc[t] = __builtin_amdgcn_mfma_f32_16x16x32_bf16(ah[t][1], bl1, acc[t], 0, 0, 0);
            acc[t] = __builtin_amdgcn_mfma_f32_16x16x32_bf16(al[t][0], bh0, acc[t], 0, 0, 0);
            acc[t] = __builtin_amdgcn_mfma_f32_16x16x32_bf16(al[t][1], bh1, acc[t], 0, 0, 0);
        }
        int kk = nt * 16 + col;
#pragma unroll
        for (int t = 0; t < 2; ++t)
#pragma unroll
            for (int q = 0; q < 4; ++q) {
                float v = acc[t][q];
                bool gt = v > b1[t][q];     // strict: first occurrence wins
                b2[t][q] = gt ? b1[t][q] : fmaxf(b2[t][q], v);
                b1[t][q] = gt ? v : b1[t][q];
                bi[t][q] = gt ? kk : bi[t][q];
            }
    }

    // reduce across the 16 codeword-columns within each 16-lane group
#pragma unroll
    for (int t = 0; t < 2; ++t)
#pragma unroll
        for (int q = 0; q < 4; ++q) {
            float v1 = b1[t][q], v2 = b2[t][q];
            int   i1 = bi[t][q];
#pragma unroll
            for (int m = 1; m <= 8; m <<= 1) {
                float o1 = __shfl_xor(v1, m);
                float o2 = __shfl_xor(v2, m);
                int   oi = __shfl_xor(i1, m);
                float nb2 = fmaxf(fminf(v1, o1), fmaxf(v2, o2));
                if (o1 > v1 || (o1 == v1 && oi < i1)) { v1 = o1; i1 = oi; }
                v2 = nb2;
            }
            b1[t][q] = v1; b2[t][q] = v2; bi[t][q] = i1;
        }

    // writes: C-layout row = (lane>>4)*4 + q, col = lane&15
#pragma unroll
    for (int t = 0; t < 2; ++t) {
        int rbase = (rt0 + t) * 16;
#pragma unroll
        for (int q = 0; q < 4; ++q) {
            if (col == q) {
                int row = rbase + grp * 4 + q;
                outidx[row] = (float)bi[t][q];
                if (b1[t][q] - b2[t][q] < TAU) {
                    int pos = atomicAdd(flagcnt, 1);
                    if (pos < FLAG_CAP) flagrows[pos] = row;
                }
            }
        }
#pragma unroll
        for (int g = 0; g < 4; ++g)
#pragma unroll
            for (int q = 0; q < 4; ++q) {
                int kidx = __shfl(bi[t][q], g * 16);
                int row  = rbase + g * 4 + q;
                outq[(size_t)row * D + lane] = embT[(size_t)kidx * D + lane];
            }
    }
}

// Phase 2: exact fp32 re-solve of flagged rows (wave per row; lane owns 8 k).
__global__ __launch_bounds__(256) void vq_fix(
    const float* __restrict__ x,
    const float* __restrict__ embT,
    const float* __restrict__ enorm,
    const int* __restrict__ flagcnt,
    const int* __restrict__ flagrows,
    float* __restrict__ outq,
    float* __restrict__ outidx) {
    int lane = threadIdx.x & 63;
    int wid  = (blockIdx.x * blockDim.x + threadIdx.x) >> 6;
    int nw   = (gridDim.x * blockDim.x) >> 6;
    int cnt  = *flagcnt; if (cnt > FLAG_CAP) cnt = FLAG_CAP;

    for (int i = wid; i < cnt; i += nw) {
        int row = __builtin_amdgcn_readfirstlane(flagrows[i]);
        const float4* x4 = (const float4*)(x + (size_t)row * D);

        float xn = 0.f;
#pragma unroll
        for (int j = 0; j < 16; ++j) {
            float4 xv = x4[j];
            xn += xv.x * xv.x + xv.y * xv.y + xv.z * xv.z + xv.w * xv.w;
        }

        float best = 3.4e38f; int bidx = 0;
#pragma unroll
        for (int kk = 0; kk < 8; ++kk) {
            int k = lane * 8 + kk;
            const float4* e4 = (const float4*)(embT + (size_t)k * D);
            float d0 = 0.f, d1 = 0.f, d2 = 0.f, d3 = 0.f;
#pragma unroll
            for (int j = 0; j < 4; ++j) {
                float4 e0 = e4[j*4+0], e1 = e4[j*4+1], e2 = e4[j*4+2], e3 = e4[j*4+3];
                float4 x0 = x4[j*4+0], x1 = x4[j*4+1], x2 = x4[j*4+2], x3 = x4[j*4+3];
                d0 += x0.x*e0.x + x0.y*e0.y + x0.z*e0.z + x0.w*e0.w;
                d1 += x1.x*e1.x + x1.y*e1.y + x1.z*e1.z + x1.w*e1.w;
                d2 += x2.x*e2.x + x2.y*e2.y + x2.z*e2.z + x2.w*e2.w;
                d3 += x3.x*e3.x + x3.y*e3.y + x3.z*e3.z + x3.w*e3.w;
            }
            float dist = (xn + enorm[k]) - 2.0f * ((d0 + d1) + (d2 + d3));
            if (dist < best) { best = dist; bidx = k; }   // ascending k in lane
        }
#pragma unroll
        for (int m = 1; m <= 32; m <<= 1) {
            float od = __shfl_xor(best, m);
            int   oi = __shfl_xor(bidx, m);
            if (od < best || (od == best && oi < bidx)) { best = od; bidx = oi; }
        }
        if (lane == 0) outidx[row] = (float)bidx;
        outq[(size_t)row * D + lane] = embT[(size_t)bidx * D + lane];
    }
}

extern "C" void kernel_launch(void* const* d_in, const int* in_sizes, int n_in,
                              void* d_out, int out_size, void* d_ws, size_t ws_size,
                              hipStream_t stream) {
    const float* x   = (const float*)d_in[0];   // (64,32,32,64) f32
    const float* emb = (const float*)d_in[1];   // (64,512) f32
    int nrows = in_sizes[0] / D;                // 65536

    char* w = (char*)d_ws;
    float*  embT   = (float*)w;   w += (size_t)K * D * 4;     // 128 KiB
    float*  enorm  = (float*)w;   w += (size_t)K * 4;         // 2 KiB
    bf16x8* bhi    = (bf16x8*)w;  w += (size_t)NT * 2 * 64 * 16; // 64 KiB
    bf16x8* blo    = (bf16x8*)w;  w += (size_t)NT * 2 * 64 * 16; // 64 KiB
    int*    flagcnt  = (int*)w;   w += 256;
    int*    flagrows = (int*)w;                               // 64 KiB

    float* outq   = (float*)d_out;
    float* outidx = (float*)d_out + (size_t)nrows * D;

    vq_prep<<<16, 256, 0, stream>>>(emb, embT, enorm, bhi, blo, flagcnt);
    vq_mfma<<<nrows / 128, 256, 0, stream>>>(x, embT, enorm, bhi, blo,
                                             outq, outidx, flagcnt, flagrows);
    vq_fix<<<128, 256, 0, stream>>>(x, embT, enorm, flagcnt, flagrows,
                                    outq, outidx);
}

// Round 6
// 49.659 us; speedup vs baseline: 10.2242x; 1.2300x over previous
//
#include <hip/hip_runtime.h>

#define D 64
#define K 512
#define NT (K / 16)          // 32 codeword tiles
#define TAU 0.01f            // proxy-margin threshold (dist-gap 0.02)

typedef float  f32x4  __attribute__((ext_vector_type(4)));
typedef short  bf16x8 __attribute__((ext_vector_type(8)));

__device__ inline unsigned short bf16_rne(float f) {
    union { float f; unsigned u; } v; v.f = f;
    unsigned r = v.u + 0x7FFFu + ((v.u >> 16) & 1u);
    return (unsigned short)(r >> 16);
}
__device__ inline float bf16_val(unsigned short b) {
    union { float f; unsigned u; } v; v.u = ((unsigned)b) << 16;
    return v.f;
}
// split 8 consecutive floats into bf16 hi + lo fragments
__device__ inline void split8(const float* p, bf16x8& h, bf16x8& l) {
    float4 a = *(const float4*)p;
    float4 b = *(const float4*)(p + 4);
    float f[8] = {a.x, a.y, a.z, a.w, b.x, b.y, b.z, b.w};
#pragma unroll
    for (int j = 0; j < 8; ++j) {
        unsigned short hb = bf16_rne(f[j]);
        float lo = f[j] - bf16_val(hb);
        h[j] = (short)hb;
        l[j] = (short)bf16_rne(lo);
    }
}

// Prep (4096 threads): fragment-linear bf16 hi/lo B-operand from emb
// ((D,K) = B[k_gemm=d][n=codeword] directly), plus embT + ||e||^2.
__global__ void vq_prep(const float* __restrict__ emb,
                        float* __restrict__ embT,
                        float* __restrict__ enorm,
                        bf16x8* __restrict__ bhi,
                        bf16x8* __restrict__ blo) {
    int t = blockIdx.x * blockDim.x + threadIdx.x;   // 0..4095
    int nt = t >> 7, c = (t >> 6) & 1, lane = t & 63;
    int k  = nt * 16 + (lane & 15);
    int d0 = c * 32 + ((lane >> 4) << 3);
    bf16x8 h, l;
#pragma unroll
    for (int j = 0; j < 8; ++j) {
        float xv = emb[(d0 + j) * K + k];
        unsigned short hb = bf16_rne(xv);
        float lo = xv - bf16_val(hb);
        h[j] = (short)hb;
        l[j] = (short)bf16_rne(lo);
    }
    int off = (nt * 2 + c) * 64 + lane;
    bhi[off] = h; blo[off] = l;

    if (t < K) {    // job 2: transpose + norms
        float s = 0.f;
#pragma unroll
        for (int d = 0; d < D; ++d) {
            float v = emb[d * K + t];
            embT[t * D + d] = v;
            s += v * v;
        }
        enorm[t] = s;
    }
}

// Fused main: wave = 2 row-tiles (32 rows) x all 512 codewords.
// acc init = -0.5*||e||^2  =>  argmax(acc) == argmin(dist); xn drops out.
// 3-product bf16-split MFMA proxy. Top-2 per row; rows with proxy margin
// < TAU are re-solved EXACTLY in fp32 by the whole wave INLINE (round-5
// post-mortem: separate vq_fix dispatch idled 42.8 us at 0.018% VALUBusy).
__global__ __launch_bounds__(256, 2) void vq_mfma(
    const float* __restrict__ x,
    const float* __restrict__ embT,
    const float* __restrict__ enorm,
    const bf16x8* __restrict__ bhi,
    const bf16x8* __restrict__ blo,
    float* __restrict__ outq,
    float* __restrict__ outidx) {
    const int tid  = threadIdx.x;
    const int wave = __builtin_amdgcn_readfirstlane(tid >> 6);
    const int lane = tid & 63;
    const int col  = lane & 15;   // A-row-in-tile for A-frag; codeword for B/C
    const int grp  = lane >> 4;
    const int rt0  = (blockIdx.x * 4 + wave) * 2;

    // A fragments (16x16x32): row m = lane&15, k = (lane>>4)*8 + j (+32*c)
    bf16x8 ah[2][2], al[2][2];
#pragma unroll
    for (int t = 0; t < 2; ++t) {
        const float* xr = x + (size_t)((rt0 + t) * 16 + col) * D + grp * 8;
        split8(xr,      ah[t][0], al[t][0]);
        split8(xr + 32, ah[t][1], al[t][1]);
    }

    float b1[2][4], b2[2][4];
    int   bi[2][4];
#pragma unroll
    for (int t = 0; t < 2; ++t)
#pragma unroll
        for (int q = 0; q < 4; ++q) {
            b1[t][q] = -3.4e38f; b2[t][q] = -3.4e38f; bi[t][q] = 0;
        }

#pragma unroll 2
    for (int nt = 0; nt < NT; ++nt) {
        int fo = (nt * 2) * 64 + lane;
        bf16x8 bh0 = bhi[fo], bh1 = bhi[fo + 64];
        bf16x8 bl0 = blo[fo], bl1 = blo[fo + 64];
        float env = enorm[nt * 16 + col] * -0.5f;
        f32x4 acc[2];
#pragma unroll
        for (int t = 0; t < 2; ++t) {
            acc[t] = f32x4{env, env, env, env};
            acc[t] = __builtin_amdgcn_mfma_f32_16x16x32_bf16(ah[t][0], bh0, acc[t], 0, 0, 0);
            acc[t] = __builtin_amdgcn_mfma_f32_16x16x32_bf16(ah[t][1], bh1, acc[t], 0, 0, 0);
            acc[t] = __builtin_amdgcn_mfma_f32_16x16x32_bf16(ah[t][0], bl0, acc[t], 0, 0, 0);
            acc[t] = __builtin_amdgcn_mfma_f32_16x16x32_bf16(ah[t][1], bl1, acc[t], 0, 0, 0);
            acc[t] = __builtin_amdgcn_mfma_f32_16x16x32_bf16(al[t][0], bh0, acc[t], 0, 0, 0);
            acc[t] = __builtin_amdgcn_mfma_f32_16x16x32_bf16(al[t][1], bh1, acc[t], 0, 0, 0);
        }
        int kk = nt * 16 + col;
#pragma unroll
        for (int t = 0; t < 2; ++t)
#pragma unroll
            for (int q = 0; q < 4; ++q) {
                float v = acc[t][q];
                bool gt = v > b1[t][q];     // strict: first occurrence wins
                b2[t][q] = gt ? b1[t][q] : fmaxf(b2[t][q], v);
                b1[t][q] = gt ? v : b1[t][q];
                bi[t][q] = gt ? kk : bi[t][q];
            }
    }

    // reduce across the 16 codeword-columns within each 16-lane group;
    // afterwards all 16 lanes of a group hold consensus (b1,b2,bi) for the
    // group's rows.
#pragma unroll
    for (int t = 0; t < 2; ++t)
#pragma unroll
        for (int q = 0; q < 4; ++q) {
            float v1 = b1[t][q], v2 = b2[t][q];
            int   i1 = bi[t][q];
#pragma unroll
            for (int m = 1; m <= 8; m <<= 1) {
                float o1 = __shfl_xor(v1, m);
                float o2 = __shfl_xor(v2, m);
                int   oi = __shfl_xor(i1, m);
                float nb2 = fmaxf(fminf(v1, o1), fmaxf(v2, o2));
                if (o1 > v1 || (o1 == v1 && oi < i1)) { v1 = o1; i1 = oi; }
                v2 = nb2;
            }
            b1[t][q] = v1; b2[t][q] = v2; bi[t][q] = i1;
        }

    // inline exact fp32 re-solve for near-tie rows (wave-uniform control).
    // Lane owns codewords k = lane*8 .. lane*8+7; same formula as the proven
    // round-3 exact kernel. Expected ~0.1 flagged rows per wave.
#pragma unroll
    for (int t = 0; t < 2; ++t)
#pragma unroll
        for (int q = 0; q < 4; ++q) {
            unsigned long long m = __ballot(b1[t][q] - b2[t][q] < TAU);
            if (m == 0ull) continue;                  // wave-uniform skip
            for (int g = 0; g < 4; ++g) {
                if (!((m >> (g * 16)) & 1ull)) continue;
                int row = (rt0 + t) * 16 + g * 4 + q; // wave-uniform
                const float4* x4 = (const float4*)(x + (size_t)row * D);
                float4 xr[16];
#pragma unroll
                for (int j = 0; j < 16; ++j) xr[j] = x4[j];
                float xn = 0.f;
#pragma unroll
                for (int j = 0; j < 16; ++j)
                    xn += xr[j].x * xr[j].x + xr[j].y * xr[j].y +
                          xr[j].z * xr[j].z + xr[j].w * xr[j].w;
                float best = 3.4e38f; int bb = 0;
#pragma unroll
                for (int kk = 0; kk < 8; ++kk) {
                    int k = lane * 8 + kk;
                    const float4* e4 = (const float4*)(embT + (size_t)k * D);
                    float d0 = 0.f, d1 = 0.f, d2 = 0.f, d3 = 0.f;
#pragma unroll
                    for (int j = 0; j < 4; ++j) {
                        float4 e0 = e4[j*4+0], e1 = e4[j*4+1];
                        float4 e2 = e4[j*4+2], e3 = e4[j*4+3];
                        d0 += xr[j*4+0].x*e0.x + xr[j*4+0].y*e0.y + xr[j*4+0].z*e0.z + xr[j*4+0].w*e0.w;
                        d1 += xr[j*4+1].x*e1.x + xr[j*4+1].y*e1.y + xr[j*4+1].z*e1.z + xr[j*4+1].w*e1.w;
                        d2 += xr[j*4+2].x*e2.x + xr[j*4+2].y*e2.y + xr[j*4+2].z*e2.z + xr[j*4+2].w*e2.w;
                        d3 += xr[j*4+3].x*e3.x + xr[j*4+3].y*e3.y + xr[j*4+3].z*e3.z + xr[j*4+3].w*e3.w;
                    }
                    float dist = (xn + enorm[k]) - 2.0f * ((d0 + d1) + (d2 + d3));
                    if (dist < best) { best = dist; bb = k; }  // ascending k
                }
#pragma unroll
                for (int mm = 1; mm <= 32; mm <<= 1) {
                    float od = __shfl_xor(best, mm);
                    int   oi = __shfl_xor(bb, mm);
                    if (od < best || (od == best && oi < bb)) { best = od; bb = oi; }
                }
                if (grp == g) bi[t][q] = bb;   // patch owner group's result
            }
        }

    // writes: C-layout row = (lane>>4)*4 + q, col = lane&15
#pragma unroll
    for (int t = 0; t < 2; ++t) {
        int rbase = (rt0 + t) * 16;
#pragma unroll
        for (int q = 0; q < 4; ++q) {
            if (col == q) {
                int row = rbase + grp * 4 + q;
                outidx[row] = (float)bi[t][q];
            }
        }
#pragma unroll
        for (int g = 0; g < 4; ++g)
#pragma unroll
            for (int q = 0; q < 4; ++q) {
                int kidx = __shfl(bi[t][q], g * 16);
                int row  = rbase + g * 4 + q;
                outq[(size_t)row * D + lane] = embT[(size_t)kidx * D + lane];
            }
    }
}

extern "C" void kernel_launch(void* const* d_in, const int* in_sizes, int n_in,
                              void* d_out, int out_size, void* d_ws, size_t ws_size,
                              hipStream_t stream) {
    const float* x   = (const float*)d_in[0];   // (64,32,32,64) f32
    const float* emb = (const float*)d_in[1];   // (64,512) f32
    int nrows = in_sizes[0] / D;                // 65536

    char* w = (char*)d_ws;
    float*  embT   = (float*)w;   w += (size_t)K * D * 4;        // 128 KiB
    float*  enorm  = (float*)w;   w += (size_t)K * 4;            // 2 KiB
    bf16x8* bhi    = (bf16x8*)w;  w += (size_t)NT * 2 * 64 * 16; // 64 KiB
    bf16x8* blo    = (bf16x8*)w;                                 // 64 KiB

    float* outq   = (float*)d_out;
    float* outidx = (float*)d_out + (size_t)nrows * D;

    vq_prep<<<16, 256, 0, stream>>>(emb, embT, enorm, bhi, blo);
    vq_mfma<<<nrows / 128, 256, 0, stream>>>(x, embT, enorm, bhi, blo,
                                             outq, outidx);
}